// Round 1
// baseline (111.854 us; speedup 1.0000x reference)
//
#include <hip/hip_runtime.h>
#include <stdint.h>

// Problem constants (from reference): x [2048][1024] f32, W [1024][4096] f32,
// out [2048][4096] f32 = x@W - 0.5*(||x_b||^2 + ||w_o||^2)
#define BATCH 2048
#define DIN   1024
#define DOUT  4096

// ---------- helpers ----------

// fp32 -> bf16 bits, round-to-nearest-even (inputs are finite normals; no NaN path)
__device__ __forceinline__ ushort f2bf(float f) {
    uint32_t u = __float_as_uint(f);
    u += 0x7fffu + ((u >> 16) & 1u);
    return (ushort)(u >> 16);
}

// async global->LDS direct copy, 16B per lane. LDS dest must be wave-uniform;
// HW writes lane i's 16B at ldsbase + i*16 (guide §5, m97/m104).
__device__ __forceinline__ void async_copy16(const void* gsrc, void* ldst) {
    __builtin_amdgcn_global_load_lds(
        reinterpret_cast<uint32_t __attribute__((address_space(1)))*>(
            reinterpret_cast<uintptr_t>(gsrc)),
        reinterpret_cast<uint32_t __attribute__((address_space(3)))*>(
            reinterpret_cast<uintptr_t>(ldst)),
        16, 0, 0);
}

typedef __bf16 bf16x8 __attribute__((ext_vector_type(8)));
typedef float  f32x4  __attribute__((ext_vector_type(4)));

// ---------- prep kernels ----------

// One block per row of x: cast to bf16, compute row sum of squares in fp32.
__global__ __launch_bounds__(256) void prep_x(const float* __restrict__ x,
                                              ushort* __restrict__ xb,
                                              float* __restrict__ xsq) {
    const int row = blockIdx.x;
    const int t = threadIdx.x;
    const float4 v = *(const float4*)(x + (size_t)row * DIN + t * 4);
    ushort4 pk;
    pk.x = f2bf(v.x); pk.y = f2bf(v.y); pk.z = f2bf(v.z); pk.w = f2bf(v.w);
    *(ushort4*)(xb + (size_t)row * DIN + t * 4) = pk;

    float s = v.x * v.x + v.y * v.y + v.z * v.z + v.w * v.w;
    #pragma unroll
    for (int off = 32; off > 0; off >>= 1) s += __shfl_down(s, off);
    __shared__ float ws[4];
    if ((t & 63) == 0) ws[t >> 6] = s;
    __syncthreads();
    if (t == 0) xsq[row] = ws[0] + ws[1] + ws[2] + ws[3];
}

// Transpose W [DIN][DOUT] f32 -> WbT [DOUT][DIN] bf16 via LDS tile, and
// accumulate column sums of squares (fp32, atomics; wsq pre-zeroed).
__global__ __launch_bounds__(256) void prep_w(const float* __restrict__ W,
                                              ushort* __restrict__ wbt,
                                              float* __restrict__ wsq) {
    __shared__ float tile[64][65];  // +1 pad: conflict-free transposed read
    const int o0 = blockIdx.x * 64;  // 64 blocks over DOUT
    const int i0 = blockIdx.y * 64;  // 16 blocks over DIN
    const int tx = threadIdx.x & 63;
    const int ty = threadIdx.x >> 6;

    float ssq = 0.f;
    #pragma unroll
    for (int r = ty; r < 64; r += 4) {           // read coalesced rows of W
        const float v = W[(size_t)(i0 + r) * DOUT + o0 + tx];
        tile[r][tx] = v;
        ssq += v * v;                            // partial for column o0+tx
    }
    atomicAdd(&wsq[o0 + tx], ssq);
    __syncthreads();
    #pragma unroll
    for (int r = ty; r < 64; r += 4) {           // write coalesced rows of W^T
        const float v = tile[tx][r];             // = W[i0+tx][o0+r]
        wbt[(size_t)(o0 + r) * DIN + i0 + tx] = f2bf(v);
    }
}

// ---------- GEMM + epilogue ----------
// A = xb [BATCH][DIN] bf16, Bt = wbt [DOUT][DIN] bf16 (W^T), out fp32.
// 128x128 tile, BK=32, 256 threads = 4 waves in 2x2, 4x4 16x16x32 MFMA per wave.
#define BM 128
#define BN 128
#define BK 32

__global__ __launch_bounds__(256, 2) void gemm_bt_epi(
    const ushort* __restrict__ A,
    const ushort* __restrict__ Bt,
    const float* __restrict__ xsq,
    const float* __restrict__ wsq,
    float* __restrict__ out) {
    __shared__ __align__(16) ushort sA[BM * BK];  // [128][32], 8 KiB
    __shared__ __align__(16) ushort sB[BN * BK];  // [128][32], 8 KiB

    const int tid  = threadIdx.x;
    const int wv   = tid >> 6;
    const int lane = tid & 63;
    const int wr = wv >> 1, wc = wv & 1;
    const int m0 = blockIdx.y * BM;
    const int n0 = blockIdx.x * BN;

    // Staging geometry (identical for sA/sB): tile row-major [128][32] ushort,
    // wave wv fills bytes [wv*2048, wv*2048+2048) as two 1024B instructions.
    // Lane l of inst q sources global (row = wv*32 + q*16 + l/4, col = (l&3)*8).
    const int st_row = wv * 32 + (lane >> 2);
    const int st_col = (lane & 3) * 8;

    const ushort* agp0 = A  + (size_t)(m0 + st_row)      * DIN + st_col;
    const ushort* agp1 = A  + (size_t)(m0 + st_row + 16) * DIN + st_col;
    const ushort* bgp0 = Bt + (size_t)(n0 + st_row)      * DIN + st_col;
    const ushort* bgp1 = Bt + (size_t)(n0 + st_row + 16) * DIN + st_col;

    ushort* sA0 = &sA[wv * 1024];
    ushort* sA1 = &sA[wv * 1024 + 512];
    ushort* sB0 = &sB[wv * 1024];
    ushort* sB1 = &sB[wv * 1024 + 512];

    f32x4 acc[4][4] = {};

    // Fragment geometry: A-op lane holds A[m=lane&15][k=(lane>>4)*8+j];
    // B-op lane holds Bt[n=lane&15][k=(lane>>4)*8+j] (k-contiguous in LDS).
    const int a_row = wr * 64 + (lane & 15);
    const int b_row = wc * 64 + (lane & 15);
    const int kq    = (lane >> 4) * 8;

    for (int kt = 0; kt < DIN; kt += BK) {
        __syncthreads();
        async_copy16(agp0 + kt, sA0);
        async_copy16(agp1 + kt, sA1);
        async_copy16(bgp0 + kt, sB0);
        async_copy16(bgp1 + kt, sB1);
        __syncthreads();  // compiler emits s_waitcnt vmcnt(0) before barrier

        bf16x8 fa[4], fb[4];
        #pragma unroll
        for (int i = 0; i < 4; ++i)
            fa[i] = *(const bf16x8*)&sA[(a_row + i * 16) * BK + kq];
        #pragma unroll
        for (int i = 0; i < 4; ++i)
            fb[i] = *(const bf16x8*)&sB[(b_row + i * 16) * BK + kq];

        #pragma unroll
        for (int mi = 0; mi < 4; ++mi)
            #pragma unroll
            for (int ni = 0; ni < 4; ++ni)
                acc[mi][ni] = __builtin_amdgcn_mfma_f32_16x16x32_bf16(
                    fa[mi], fb[ni], acc[mi][ni], 0, 0, 0);
    }

    // Epilogue. C/D layout (measured m89/m91): col = lane&15, row = (lane>>4)*4 + r.
    const int er = (lane >> 4) * 4;
    const int ec = lane & 15;
    #pragma unroll
    for (int mi = 0; mi < 4; ++mi) {
        const int row = m0 + wr * 64 + mi * 16 + er;
        #pragma unroll
        for (int ni = 0; ni < 4; ++ni) {
            const int col = n0 + wc * 64 + ni * 16 + ec;
            const float wterm = wsq[col];
            #pragma unroll
            for (int r = 0; r < 4; ++r) {
                out[(size_t)(row + r) * DOUT + col] =
                    acc[mi][ni][r] - 0.5f * (xsq[row + r] + wterm);
            }
        }
    }
}

// ---------- launch ----------

extern "C" void kernel_launch(void* const* d_in, const int* in_sizes, int n_in,
                              void* d_out, int out_size, void* d_ws, size_t ws_size,
                              hipStream_t stream) {
    const float* x = (const float*)d_in[0];
    const float* W = (const float*)d_in[1];
    float* out = (float*)d_out;

    // Workspace layout (needs ~12.02 MiB):
    //   [0, 4MiB)        xb  : bf16 x   [2048][1024]
    //   [4MiB, 12MiB)    wbt : bf16 W^T [4096][1024]
    //   [12MiB, +8KiB)   xsq : f32 [2048]
    //   [+16KiB, +32KiB) wsq : f32 [4096]
    char* ws = (char*)d_ws;
    ushort* xb  = (ushort*)ws;
    ushort* wbt = (ushort*)(ws + (4u << 20));
    float*  xsq = (float*)(ws + (12u << 20));
    float*  wsq = (float*)(ws + (12u << 20) + (16u << 10));

    hipMemsetAsync(wsq, 0, DOUT * sizeof(float), stream);  // atomics target
    prep_x<<<BATCH, 256, 0, stream>>>(x, xb, xsq);
    prep_w<<<dim3(DOUT / 64, DIN / 64), 256, 0, stream>>>(W, wbt, wsq);
    gemm_bt_epi<<<dim3(DOUT / BN, BATCH / BM), 256, 0, stream>>>(xb, wbt, xsq, wsq, out);
}